// Round 21
// baseline (178.725 us; speedup 1.0000x reference)
//
#include <hip/hip_runtime.h>
#include <hip/hip_bf16.h>
#include <stdint.h>

#define NNODE  17
#define FDIM   64
#define NBLOCK 1024
#define GPW    16           // graphs per wave: 1024 blk x 4 waves x 16 = 65536
#define SROW   68           // wave-strip col stride in u16 (136 B; conflict-free)
#define WSTR   132          // W2T staging stride in u16

typedef __attribute__((ext_vector_type(4)))  short short4v;
typedef __attribute__((ext_vector_type(8)))  short short8v;
typedef __attribute__((ext_vector_type(4)))  float f32x4v;
typedef __attribute__((ext_vector_type(16))) float f32x16;
typedef __attribute__((ext_vector_type(2)))  unsigned int uint2v;

__device__ __forceinline__ uint32_t bf16b(float f) {
    uint32_t u = __float_as_uint(f);
    return (u + 0x7fffu + ((u >> 16) & 1u)) >> 16;   // RNE (prologue only)
}
__device__ __forceinline__ uint32_t cvtpk(float lo, float hi) {   // v_cvt_pk_bf16_f32 (RNE)
    __hip_bfloat162 b = __float22bfloat162_rn(make_float2(lo, hi));
    return *reinterpret_cast<uint32_t*>(&b);
}
__device__ __forceinline__ short8v ld8(const uint16_t* p) {   // 2x ds_read_b64
    short4v lo = *(const short4v*)p;
    short4v hi = *(const short4v*)(p + 4);
    return __builtin_shufflevector(lo, hi, 0, 1, 2, 3, 4, 5, 6, 7);
}
__device__ __forceinline__ short8v mk8(uint32_t w0, uint32_t w1, uint32_t w2, uint32_t w3) {
    union { uint32_t u[4]; short8v v; } c;
    c.u[0] = w0; c.u[1] = w1; c.u[2] = w2; c.u[3] = w3;
    return c.v;
}

// R19 (110.7us, nt-stores + cached loads) + CLEAN depth-2 prefetch (pA/pB) +
// sequential-hf compute (halves live accumulators 64->32 regs to pay for pB).
__global__ __launch_bounds__(256, 2) void egc_kernel(
    const float* __restrict__ x, const float* __restrict__ adj,
    const float* __restrict__ wself, const float* __restrict__ wneigh,
    const float* __restrict__ bias, float* __restrict__ out)
{
    __shared__ uint16_t sMem[4 * 32 * SROW];   // 4 wave strips (loop); W2T alias (prologue)
    __shared__ float sAdj[NNODE * NNODE];
    __shared__ float sBias[FDIM];

    const int t  = threadIdx.x;
    const int l  = t & 63;
    const int wv = t >> 6;
    const int n_ = l & 31;       // A.m / B.n / D.col
    const int h_ = l >> 5;       // k-half / D-row +4

    const int    gw    = blockIdx.x * 4 + wv;
    const size_t gbase = (size_t)gw * GPW;
    const f32x4v* xg0  = (const f32x4v*)x + gbase * 272;

    // depth-2 prefetch state
    f32x4v pA[5], pB[5];
    #define LOADQ(P, IDX) {                                                        \
        const f32x4v* xq = xg0 + (size_t)(IDX) * 272;                              \
        P[0] = xq[l];       P[1] = xq[l + 64]; P[2] = xq[l + 128];                 \
        P[3] = xq[l + 192]; P[4] = xq[256 + (l & 15)];  }
    LOADQ(pA, 0)
    LOADQ(pB, 1)

    // ---- prologue: stage W2T[o][k] (k<64: Ws[k][o] else Wn[k-64][o]) into sMem
    for (int idx = t; idx < FDIM * 128; idx += 256) {
        int o = idx >> 7, k = idx & 127;
        float v = (k < 64) ? wself[k * 64 + o] : wneigh[(k - 64) * 64 + o];
        sMem[o * WSTR + k] = (uint16_t)bf16b(v);
    }
    for (int i = t; i < NNODE * NNODE; i += 256) sAdj[i] = adj[i];
    if (t < FDIM) sBias[t] = bias[t];
    __syncthreads();

    // W B-frags: B[k=16ks+8h_+e][n=32hf+n_]
    short8v wS[2][4], wN[2][4];
    #pragma unroll
    for (int hf = 0; hf < 2; ++hf)
        #pragma unroll
        for (int ks = 0; ks < 4; ++ks) {
            wS[hf][ks] = ld8(&sMem[(32 * hf + n_) * WSTR + 16 * ks + 8 * h_]);
            wN[hf][ks] = ld8(&sMem[(32 * hf + n_) * WSTR + 64 + 16 * ks + 8 * h_]);
        }
    const float bias0 = sBias[n_], bias1 = sBias[32 + n_];

    // adj A-frags: A[m=n_][k=16ks+8h_+e] = adj[n_][k], explicit zero pad (no NaN)
    short8v adjA[2];
    #pragma unroll
    for (int ks = 0; ks < 2; ++ks) {
        short8v v;
        #pragma unroll
        for (int e = 0; e < 8; ++e) {
            int k = 16 * ks + 8 * h_ + e;
            float a = (n_ < NNODE && k < NNODE) ? sAdj[n_ * NNODE + k] : 0.f;
            v[e] = (short)bf16b(a);
        }
        adjA[ks] = v;
    }
    __syncthreads();
    // zero all strips once (pad rows 17..31 stay zero forever -> h pad rows finite-zero)
    for (int i = t; i < 4 * 32 * SROW; i += 256) sMem[i] = 0;
    __syncthreads();
    // ---- no __syncthreads below this line ----

    uint16_t* strip = &sMem[wv * 32 * SROW];
    float* outg = out + gbase * (size_t)(NNODE * FDIM);

    #define STAGE(P) {                                                             \
        uint2 pk; int idx, row, c4;                                                \
        idx = l;       row = idx >> 4; c4 = (idx & 15) << 2;                       \
        pk.x = cvtpk(P[0][0], P[0][1]); pk.y = cvtpk(P[0][2], P[0][3]);            \
        *(uint2*)&strip[row * SROW + c4] = pk;                                     \
        idx = l + 64;  row = idx >> 4; c4 = (idx & 15) << 2;                       \
        pk.x = cvtpk(P[1][0], P[1][1]); pk.y = cvtpk(P[1][2], P[1][3]);            \
        *(uint2*)&strip[row * SROW + c4] = pk;                                     \
        idx = l + 128; row = idx >> 4; c4 = (idx & 15) << 2;                       \
        pk.x = cvtpk(P[2][0], P[2][1]); pk.y = cvtpk(P[2][2], P[2][3]);            \
        *(uint2*)&strip[row * SROW + c4] = pk;                                     \
        idx = l + 192; row = idx >> 4; c4 = (idx & 15) << 2;                       \
        pk.x = cvtpk(P[3][0], P[3][1]); pk.y = cvtpk(P[3][2], P[3][3]);            \
        *(uint2*)&strip[row * SROW + c4] = pk;                                     \
        if (l < 16) {                                                              \
            pk.x = cvtpk(P[4][0], P[4][1]); pk.y = cvtpk(P[4][2], P[4][3]);        \
            *(uint2*)&strip[16 * SROW + (l << 2)] = pk;                            \
        }                                                                          \
    }

#if __has_builtin(__builtin_amdgcn_permlane32_swap)
    #define HTRANS(sv, hv, ks2)                                                    \
        {                                                                          \
            const int rb = 8 * (ks2);                                              \
            uint32_t A01 = cvtpk(hv[rb + 0], hv[rb + 1]);                          \
            uint32_t C23 = cvtpk(hv[rb + 2], hv[rb + 3]);                          \
            uint32_t B45 = cvtpk(hv[rb + 4], hv[rb + 5]);                          \
            uint32_t D67 = cvtpk(hv[rb + 6], hv[rb + 7]);                          \
            uint2v rA = __builtin_amdgcn_permlane32_swap(A01, B45, false, false);  \
            uint2v rC = __builtin_amdgcn_permlane32_swap(C23, D67, false, false);  \
            sv = __builtin_amdgcn_mfma_f32_32x32x16_bf16(                          \
                     adjA[ks2], mk8(rA[0], rC[0], rA[1], rC[1]), sv, 0, 0, 0);     \
        }
#else
    #define HTRANS(sv, hv, ks2)                                                    \
        {                                                                          \
            const int rb = 8 * (ks2);                                              \
            float o0_ = __shfl_xor(h_ ? hv[rb + 0] : hv[rb + 4], 32);              \
            float o1_ = __shfl_xor(h_ ? hv[rb + 1] : hv[rb + 5], 32);              \
            float o2_ = __shfl_xor(h_ ? hv[rb + 2] : hv[rb + 6], 32);              \
            float o3_ = __shfl_xor(h_ ? hv[rb + 3] : hv[rb + 7], 32);              \
            uint32_t l01 = cvtpk(hv[rb + 0], hv[rb + 1]);                          \
            uint32_t l23 = cvtpk(hv[rb + 2], hv[rb + 3]);                          \
            uint32_t l45 = cvtpk(hv[rb + 4], hv[rb + 5]);                          \
            uint32_t l67 = cvtpk(hv[rb + 6], hv[rb + 7]);                          \
            uint32_t o01 = cvtpk(o0_, o1_);                                        \
            uint32_t o23 = cvtpk(o2_, o3_);                                        \
            uint32_t w0 = h_ ? o01 : l01;                                          \
            uint32_t w1 = h_ ? o23 : l23;                                          \
            uint32_t w2 = h_ ? l45 : o01;                                          \
            uint32_t w3 = h_ ? l67 : o23;                                          \
            sv = __builtin_amdgcn_mfma_f32_32x32x16_bf16(                          \
                     adjA[ks2], mk8(w0, w1, w2, w3), sv, 0, 0, 0);                 \
        }
#endif

    // sequential hf halves: live acc = 32 regs (pays for pB's 20)
    #define COMPUTE(OG) {                                                          \
        short8v a0 = ld8(&strip[n_ * SROW + 0  + 8 * h_]);                         \
        short8v a1 = ld8(&strip[n_ * SROW + 16 + 8 * h_]);                         \
        short8v a2 = ld8(&strip[n_ * SROW + 32 + 8 * h_]);                         \
        short8v a3 = ld8(&strip[n_ * SROW + 48 + 8 * h_]);                         \
        _Pragma("unroll")                                                          \
        for (int hf = 0; hf < 2; ++hf) {                                           \
            const float bb = hf ? bias1 : bias0;                                   \
            f32x16 s, h;                                                           \
            _Pragma("unroll")                                                      \
            for (int r2 = 0; r2 < 16; ++r2) { s[r2] = bb; h[r2] = 0.f; }           \
            s = __builtin_amdgcn_mfma_f32_32x32x16_bf16(a0, wS[hf][0], s, 0,0,0);  \
            h = __builtin_amdgcn_mfma_f32_32x32x16_bf16(a0, wN[hf][0], h, 0,0,0);  \
            s = __builtin_amdgcn_mfma_f32_32x32x16_bf16(a1, wS[hf][1], s, 0,0,0);  \
            h = __builtin_amdgcn_mfma_f32_32x32x16_bf16(a1, wN[hf][1], h, 0,0,0);  \
            s = __builtin_amdgcn_mfma_f32_32x32x16_bf16(a2, wS[hf][2], s, 0,0,0);  \
            h = __builtin_amdgcn_mfma_f32_32x32x16_bf16(a2, wN[hf][2], h, 0,0,0);  \
            s = __builtin_amdgcn_mfma_f32_32x32x16_bf16(a3, wS[hf][3], s, 0,0,0);  \
            h = __builtin_amdgcn_mfma_f32_32x32x16_bf16(a3, wN[hf][3], h, 0,0,0);  \
            HTRANS(s, h, 0)                                                        \
            HTRANS(s, h, 1)                                                        \
            _Pragma("unroll")                                                      \
            for (int r2 = 0; r2 < 9; ++r2) {                                       \
                int row = (r2 & 3) + 8 * (r2 >> 2) + 4 * h_;                       \
                if (row < NNODE)                                                   \
                    __builtin_nontemporal_store(s[r2], &(OG)[row * 64 + 32*hf + n_]); \
            }                                                                      \
        }                                                                          \
    }

    #pragma unroll 1
    for (int gi = 0; gi < GPW; gi += 2) {
        int nxA = gi + 2 < GPW ? gi + 2 : GPW - 1;   // clamped: branch-free tail
        int nxB = gi + 3 < GPW ? gi + 3 : GPW - 1;
        STAGE(pA)                                    // waits pA (oldest in FIFO)
        LOADQ(pA, nxA)                               // depth-2: re-arm A
        COMPUTE(outg + (size_t)gi * (NNODE * FDIM))
        STAGE(pB)
        LOADQ(pB, nxB)
        COMPUTE(outg + (size_t)(gi + 1) * (NNODE * FDIM))
    }

    #undef LOADQ
    #undef STAGE
    #undef HTRANS
    #undef COMPUTE
}

extern "C" void kernel_launch(void* const* d_in, const int* in_sizes, int n_in,
                              void* d_out, int out_size, void* d_ws, size_t ws_size,
                              hipStream_t stream) {
    (void)in_sizes; (void)n_in; (void)d_ws; (void)ws_size; (void)out_size;
    const float* x      = (const float*)d_in[0];
    const float* adj    = (const float*)d_in[1];
    const float* wself  = (const float*)d_in[2];
    const float* wneigh = (const float*)d_in[3];
    const float* bias   = (const float*)d_in[4];
    float* out = (float*)d_out;
    egc_kernel<<<NBLOCK, 256, 0, stream>>>(x, adj, wself, wneigh, bias, out);
}

// Round 22
// 108.946 us; speedup vs baseline: 1.6405x; 1.6405x over previous
//
#include <hip/hip_runtime.h>
#include <hip/hip_bf16.h>
#include <stdint.h>

#define NNODE  17
#define FDIM   64
#define NBLOCK 1024
#define GPW    16           // graphs per wave: 1024 blk x 4 waves x 16 = 65536
#define SROW   68           // wave-strip col stride in u16 (136 B; conflict-free)
#define WSTR   132          // W2T staging stride in u16

typedef __attribute__((ext_vector_type(4)))  short short4v;
typedef __attribute__((ext_vector_type(8)))  short short8v;
typedef __attribute__((ext_vector_type(4)))  float f32x4v;
typedef __attribute__((ext_vector_type(16))) float f32x16;
typedef __attribute__((ext_vector_type(2)))  unsigned int uint2v;

__device__ __forceinline__ uint32_t bf16b(float f) {
    uint32_t u = __float_as_uint(f);
    return (u + 0x7fffu + ((u >> 16) & 1u)) >> 16;   // RNE (prologue only)
}
__device__ __forceinline__ uint32_t cvtpk(float lo, float hi) {   // v_cvt_pk_bf16_f32 (RNE)
    __hip_bfloat162 b = __float22bfloat162_rn(make_float2(lo, hi));
    return *reinterpret_cast<uint32_t*>(&b);
}
__device__ __forceinline__ short8v ld8(const uint16_t* p) {   // 2x ds_read_b64
    short4v lo = *(const short4v*)p;
    short4v hi = *(const short4v*)(p + 4);
    return __builtin_shufflevector(lo, hi, 0, 1, 2, 3, 4, 5, 6, 7);
}
__device__ __forceinline__ short8v mk8(uint32_t w0, uint32_t w1, uint32_t w2, uint32_t w3) {
    union { uint32_t u[4]; short8v v; } c;
    c.u[0] = w0; c.u[1] = w1; c.u[2] = w2; c.u[3] = w3;
    return c.v;
}

// FINAL (R19, measured 110.7us / R20-equivalent 110.5us): barrier-free per-wave
// loop, depth-1 register prefetch, cached x loads (L3 retains ~146MB across
// replays), nt stores (write-once output must not evict x from L2/L3).
__global__ __launch_bounds__(256, 2) void egc_kernel(
    const float* __restrict__ x, const float* __restrict__ adj,
    const float* __restrict__ wself, const float* __restrict__ wneigh,
    const float* __restrict__ bias, float* __restrict__ out)
{
    __shared__ uint16_t sMem[4 * 32 * SROW];   // 4 wave strips (loop); W2T alias (prologue)
    __shared__ float sAdj[NNODE * NNODE];
    __shared__ float sBias[FDIM];

    const int t  = threadIdx.x;
    const int l  = t & 63;
    const int wv = t >> 6;
    const int n_ = l & 31;       // A.m / B.n / D.col
    const int h_ = l >> 5;       // k-half / D-row +4

    const int    gw    = blockIdx.x * 4 + wv;
    const size_t gbase = (size_t)gw * GPW;

    // issue graph-0 prefetch immediately (in flight across the prologue)
    const f32x4v* xg = (const f32x4v*)x + gbase * 272;
    f32x4v pf0, pf1, pf2, pf3, pf4;
    pf0 = xg[l];       pf1 = xg[l + 64];
    pf2 = xg[l + 128]; pf3 = xg[l + 192];
    if (l < 16) pf4 = xg[256 + l];

    // ---- prologue: stage W2T[o][k] (k<64: Ws[k][o] else Wn[k-64][o]) into sMem
    for (int idx = t; idx < FDIM * 128; idx += 256) {
        int o = idx >> 7, k = idx & 127;
        float v = (k < 64) ? wself[k * 64 + o] : wneigh[(k - 64) * 64 + o];
        sMem[o * WSTR + k] = (uint16_t)bf16b(v);
    }
    for (int i = t; i < NNODE * NNODE; i += 256) sAdj[i] = adj[i];
    if (t < FDIM) sBias[t] = bias[t];
    __syncthreads();

    // W B-frags: B[k=16ks+8h_+e][n=32nt+n_]
    short8v wS[2][4], wN[2][4];
    #pragma unroll
    for (int nt = 0; nt < 2; ++nt)
        #pragma unroll
        for (int ks = 0; ks < 4; ++ks) {
            wS[nt][ks] = ld8(&sMem[(32 * nt + n_) * WSTR + 16 * ks + 8 * h_]);
            wN[nt][ks] = ld8(&sMem[(32 * nt + n_) * WSTR + 64 + 16 * ks + 8 * h_]);
        }
    const float bias0 = sBias[n_], bias1 = sBias[32 + n_];

    // adj A-frags: A[m=n_][k=16ks+8h_+e] = adj[n_][k], explicit zero pad (no NaN)
    short8v adjA[2];
    #pragma unroll
    for (int ks = 0; ks < 2; ++ks) {
        short8v v;
        #pragma unroll
        for (int e = 0; e < 8; ++e) {
            int k = 16 * ks + 8 * h_ + e;
            float a = (n_ < NNODE && k < NNODE) ? sAdj[n_ * NNODE + k] : 0.f;
            v[e] = (short)bf16b(a);
        }
        adjA[ks] = v;
    }
    __syncthreads();
    // zero all strips once (pad rows 17..31 stay zero forever -> h pad rows finite-zero)
    for (int i = t; i < 4 * 32 * SROW; i += 256) sMem[i] = 0;
    __syncthreads();
    // ---- no __syncthreads below this line ----

    uint16_t* strip = &sMem[wv * 32 * SROW];
    float* outg = out + gbase * (size_t)(NNODE * FDIM);

    for (int g = 0; g < GPW; ++g) {
        // stage pf -> strip rows 0..16 (b64 writes; same-wave LDS is FIFO-ordered)
        {
            uint2 pk; int idx, row, c4;
            idx = l;       row = idx >> 4; c4 = (idx & 15) << 2;
            pk.x = cvtpk(pf0[0], pf0[1]); pk.y = cvtpk(pf0[2], pf0[3]);
            *(uint2*)&strip[row * SROW + c4] = pk;
            idx = l + 64;  row = idx >> 4; c4 = (idx & 15) << 2;
            pk.x = cvtpk(pf1[0], pf1[1]); pk.y = cvtpk(pf1[2], pf1[3]);
            *(uint2*)&strip[row * SROW + c4] = pk;
            idx = l + 128; row = idx >> 4; c4 = (idx & 15) << 2;
            pk.x = cvtpk(pf2[0], pf2[1]); pk.y = cvtpk(pf2[2], pf2[3]);
            *(uint2*)&strip[row * SROW + c4] = pk;
            idx = l + 192; row = idx >> 4; c4 = (idx & 15) << 2;
            pk.x = cvtpk(pf3[0], pf3[1]); pk.y = cvtpk(pf3[2], pf3[3]);
            *(uint2*)&strip[row * SROW + c4] = pk;
            if (l < 16) {
                pk.x = cvtpk(pf4[0], pf4[1]); pk.y = cvtpk(pf4[2], pf4[3]);
                *(uint2*)&strip[16 * SROW + (l << 2)] = pk;
            }
        }
        // prefetch next graph (hides HBM latency under MFMA below)
        if (g + 1 < GPW) {
            xg += 272;
            pf0 = xg[l];       pf1 = xg[l + 64];
            pf2 = xg[l + 128]; pf3 = xg[l + 192];
            if (l < 16) pf4 = xg[256 + l];
        }

        // A-frags: A[m=node n_][k=16ks+8h_+e]  (rows 17..31 = zero pad)
        short8v a0 = ld8(&strip[n_ * SROW + 0  + 8 * h_]);
        short8v a1 = ld8(&strip[n_ * SROW + 16 + 8 * h_]);
        short8v a2 = ld8(&strip[n_ * SROW + 32 + 8 * h_]);
        short8v a3 = ld8(&strip[n_ * SROW + 48 + 8 * h_]);

        f32x16 s0, s1, h0, h1;
        #pragma unroll
        for (int r = 0; r < 16; ++r) { s0[r] = bias0; s1[r] = bias1; h0[r] = 0.f; h1[r] = 0.f; }

        // s = x@Ws + bias ; h = x@Wn   (K=64, 16 MFMA)
        s0 = __builtin_amdgcn_mfma_f32_32x32x16_bf16(a0, wS[0][0], s0, 0, 0, 0);
        s1 = __builtin_amdgcn_mfma_f32_32x32x16_bf16(a0, wS[1][0], s1, 0, 0, 0);
        h0 = __builtin_amdgcn_mfma_f32_32x32x16_bf16(a0, wN[0][0], h0, 0, 0, 0);
        h1 = __builtin_amdgcn_mfma_f32_32x32x16_bf16(a0, wN[1][0], h1, 0, 0, 0);
        s0 = __builtin_amdgcn_mfma_f32_32x32x16_bf16(a1, wS[0][1], s0, 0, 0, 0);
        s1 = __builtin_amdgcn_mfma_f32_32x32x16_bf16(a1, wS[1][1], s1, 0, 0, 0);
        h0 = __builtin_amdgcn_mfma_f32_32x32x16_bf16(a1, wN[0][1], h0, 0, 0, 0);
        h1 = __builtin_amdgcn_mfma_f32_32x32x16_bf16(a1, wN[1][1], h1, 0, 0, 0);
        s0 = __builtin_amdgcn_mfma_f32_32x32x16_bf16(a2, wS[0][2], s0, 0, 0, 0);
        s1 = __builtin_amdgcn_mfma_f32_32x32x16_bf16(a2, wS[1][2], s1, 0, 0, 0);
        h0 = __builtin_amdgcn_mfma_f32_32x32x16_bf16(a2, wN[0][2], h0, 0, 0, 0);
        h1 = __builtin_amdgcn_mfma_f32_32x32x16_bf16(a2, wN[1][2], h1, 0, 0, 0);
        s0 = __builtin_amdgcn_mfma_f32_32x32x16_bf16(a3, wS[0][3], s0, 0, 0, 0);
        s1 = __builtin_amdgcn_mfma_f32_32x32x16_bf16(a3, wS[1][3], s1, 0, 0, 0);
        h0 = __builtin_amdgcn_mfma_f32_32x32x16_bf16(a3, wN[0][3], h0, 0, 0, 0);
        h1 = __builtin_amdgcn_mfma_f32_32x32x16_bf16(a3, wN[1][3], h1, 0, 0, 0);

        // out += adj@h : h (D-layout) -> B-frag via cvt_pk + permlane32_swap
#if __has_builtin(__builtin_amdgcn_permlane32_swap)
        #define HB_ADJ(SACC, HACC)                                                        \
        {                                                                                  \
            _Pragma("unroll")                                                              \
            for (int ks2 = 0; ks2 < 2; ++ks2) {                                            \
                const int rb = 8 * ks2;                                                    \
                uint32_t A01 = cvtpk(HACC[rb + 0], HACC[rb + 1]);                          \
                uint32_t C23 = cvtpk(HACC[rb + 2], HACC[rb + 3]);                          \
                uint32_t B45 = cvtpk(HACC[rb + 4], HACC[rb + 5]);                          \
                uint32_t D67 = cvtpk(HACC[rb + 6], HACC[rb + 7]);                          \
                uint2v rA = __builtin_amdgcn_permlane32_swap(A01, B45, false, false);      \
                uint2v rC = __builtin_amdgcn_permlane32_swap(C23, D67, false, false);      \
                SACC = __builtin_amdgcn_mfma_f32_32x32x16_bf16(                            \
                    adjA[ks2], mk8(rA[0], rC[0], rA[1], rC[1]), SACC, 0, 0, 0);            \
            }                                                                              \
        }
#else
        #define HB_ADJ(SACC, HACC)                                                        \
        {                                                                                  \
            _Pragma("unroll")                                                              \
            for (int ks2 = 0; ks2 < 2; ++ks2) {                                            \
                const int rb = 8 * ks2;                                                    \
                float o0_ = __shfl_xor(h_ ? HACC[rb + 0] : HACC[rb + 4], 32);              \
                float o1_ = __shfl_xor(h_ ? HACC[rb + 1] : HACC[rb + 5], 32);              \
                float o2_ = __shfl_xor(h_ ? HACC[rb + 2] : HACC[rb + 6], 32);              \
                float o3_ = __shfl_xor(h_ ? HACC[rb + 3] : HACC[rb + 7], 32);              \
                uint32_t l01 = cvtpk(HACC[rb + 0], HACC[rb + 1]);                          \
                uint32_t l23 = cvtpk(HACC[rb + 2], HACC[rb + 3]);                          \
                uint32_t l45 = cvtpk(HACC[rb + 4], HACC[rb + 5]);                          \
                uint32_t l67 = cvtpk(HACC[rb + 6], HACC[rb + 7]);                          \
                uint32_t o01 = cvtpk(o0_, o1_);                                            \
                uint32_t o23 = cvtpk(o2_, o3_);                                            \
                uint32_t w0 = h_ ? o01 : l01;                                              \
                uint32_t w1 = h_ ? o23 : l23;                                              \
                uint32_t w2 = h_ ? l45 : o01;                                              \
                uint32_t w3 = h_ ? l67 : o23;                                              \
                SACC = __builtin_amdgcn_mfma_f32_32x32x16_bf16(                            \
                    adjA[ks2], mk8(w0, w1, w2, w3), SACC, 0, 0, 0);                        \
            }                                                                              \
        }
#endif
        HB_ADJ(s0, h0)
        HB_ADJ(s1, h1)
        #undef HB_ADJ

        // store: D[row=(r&3)+8*(r>>2)+4h_][col n_]; nt stores (no write-allocate)
        {
            float* og = outg + (size_t)g * (NNODE * FDIM);
            #pragma unroll
            for (int r = 0; r < 9; ++r) {
                int row = (r & 3) + 8 * (r >> 2) + 4 * h_;
                if (row < NNODE) {
                    __builtin_nontemporal_store(s0[r], &og[row * 64 + n_]);
                    __builtin_nontemporal_store(s1[r], &og[row * 64 + 32 + n_]);
                }
            }
        }
    }
}

extern "C" void kernel_launch(void* const* d_in, const int* in_sizes, int n_in,
                              void* d_out, int out_size, void* d_ws, size_t ws_size,
                              hipStream_t stream) {
    (void)in_sizes; (void)n_in; (void)d_ws; (void)ws_size; (void)out_size;
    const float* x      = (const float*)d_in[0];
    const float* adj    = (const float*)d_in[1];
    const float* wself  = (const float*)d_in[2];
    const float* wneigh = (const float*)d_in[3];
    const float* bias   = (const float*)d_in[4];
    float* out = (float*)d_out;
    egc_kernel<<<NBLOCK, 256, 0, stream>>>(x, adj, wself, wneigh, bias, out);
}